// Round 13
// baseline (205.108 us; speedup 1.0000x reference)
//
#include <hip/hip_runtime.h>
#include <hip/hip_bf16.h>

// B=2, C=8, L=1024, H=512
// out[((b*1024+l)*1024+m)*8 + c] = a[b,c,l] + bb[b,c,m] + sum_h start*v4*end
//
// Round 13: LDS-free K-loop. prep_k (verified) pre-packs bf16 A(v4-folded)/B.
// gemm3_k loads MFMA fragments DIRECTLY from global (16B/lane, 64B-sector
// coalesced) -- no LDS, no vmcnt(0) drain, no bank conflicts in the K-loop;
// pure load+MFMA loop lets the compiler software-pipeline with counted vmcnt.
// Geometry + epilogue identical to R12 (verified): 32l x 128m x 8c, grid 512,
// wave = c-plane, LDS transpose epilogue for full-line writes.
// Fallback path (ws too small): round-10 verified kernels unchanged.

typedef short bf16x8 __attribute__((ext_vector_type(8)));
typedef float f32x4 __attribute__((ext_vector_type(4)));

__device__ __forceinline__ unsigned short f2bf(float x) {
    unsigned int u = __float_as_uint(x);
    u += 0x7fffu + ((u >> 16) & 1u);   // round-to-nearest-even
    return (unsigned short)(u >> 16);
}

__device__ __forceinline__ uint4 pack8(float4 a, float4 b) {
    uint4 r;
    r.x = (unsigned)f2bf(a.x) | ((unsigned)f2bf(a.y) << 16);
    r.y = (unsigned)f2bf(a.z) | ((unsigned)f2bf(a.w) << 16);
    r.z = (unsigned)f2bf(b.x) | ((unsigned)f2bf(b.y) << 16);
    r.w = (unsigned)f2bf(b.z) | ((unsigned)f2bf(b.w) << 16);
    return r;
}

// ---------------- prep: row dots + bf16 conversion (R11 verified, unchanged) ----------------
__global__ __launch_bounds__(256) void prep_k(const float* __restrict__ sh,
                                              const float* __restrict__ eh,
                                              const float* __restrict__ v,
                                              float* __restrict__ sums,
                                              unsigned short* __restrict__ Aw,
                                              unsigned short* __restrict__ Bw) {
    const int gid  = blockIdx.x * 256 + threadIdx.x;
    const int row  = gid >> 6;
    const int lane = gid & 63;
    const int h    = lane * 8;

    const float* ps = sh + (size_t)row * 512 + h;
    const float* pe = eh + (size_t)row * 512 + h;
    float4 s0 = *(const float4*)ps;       float4 s1 = *(const float4*)(ps + 4);
    float4 e0 = *(const float4*)pe;       float4 e1 = *(const float4*)(pe + 4);
    float4 v10 = *(const float4*)(v + h);        float4 v11 = *(const float4*)(v + h + 4);
    float4 v20 = *(const float4*)(v + 512 + h);  float4 v21 = *(const float4*)(v + 512 + h + 4);
    float4 v30 = *(const float4*)(v + 1024 + h); float4 v31 = *(const float4*)(v + 1024 + h + 4);
    float4 v40 = *(const float4*)(v + 1536 + h); float4 v41 = *(const float4*)(v + 1536 + h + 4);

    float da = s0.x*(v10.x+v30.x) + s0.y*(v10.y+v30.y) + s0.z*(v10.z+v30.z) + s0.w*(v10.w+v30.w)
             + s1.x*(v11.x+v31.x) + s1.y*(v11.y+v31.y) + s1.z*(v11.z+v31.z) + s1.w*(v11.w+v31.w);
    float db = e0.x*(v20.x-v30.x) + e0.y*(v20.y-v30.y) + e0.z*(v20.z-v30.z) + e0.w*(v20.w-v30.w)
             + e1.x*(v21.x-v31.x) + e1.y*(v21.y-v31.y) + e1.z*(v21.z-v31.z) + e1.w*(v21.w-v31.w);

    float4 a0 = s0, a1 = s1;
    a0.x *= v40.x; a0.y *= v40.y; a0.z *= v40.z; a0.w *= v40.w;
    a1.x *= v41.x; a1.y *= v41.y; a1.z *= v41.z; a1.w *= v41.w;
    *(uint4*)&Aw[(size_t)row * 512 + h] = pack8(a0, a1);
    *(uint4*)&Bw[(size_t)row * 512 + h] = pack8(e0, e1);

    #pragma unroll
    for (int off = 32; off >= 1; off >>= 1) {
        da += __shfl_down(da, off, 64);
        db += __shfl_down(db, off, 64);
    }
    if (lane == 0) {
        sums[row]         = da;
        sums[16384 + row] = db;
    }
}

// ---------------- gemm3: direct-from-global MFMA fragments, LDS-free K-loop ----------------
// grid 512: bid = lt*16 + b*8 + mt  (bid%8 = mt -> B-panel users share an XCD)
__global__ __launch_bounds__(512) void gemm3_k(const unsigned short* __restrict__ Aw,
                                               const unsigned short* __restrict__ Bw,
                                               const float* __restrict__ sums,
                                               float* __restrict__ out) {
    // LDS: epilogue transpose scratch only (16 rows x 1153 floats = 73.8 KB)
    __shared__ __align__(16) float smE[16 * 1153];

    const int t    = threadIdx.x;
    const int bid  = blockIdx.x;
    const int mt   = bid & 7;
    const int b    = (bid >> 3) & 1;
    const int lt   = bid >> 4;            // 0..31
    const int lbase = lt * 32, mbase = mt * 128;

    const int lane = t & 63, wave = t >> 6;   // wave = c-plane (0..7)
    const int ln15 = lane & 15, quad = lane >> 4;

    // per-lane fragment base: row ln15 (within 16-row group), k-block quad
    const unsigned short* baseA =
        Aw + ((size_t)(b * 8 + wave) * 1024 + lbase + ln15) * 512 + quad * 8;
    const unsigned short* baseB =
        Bw + ((size_t)(b * 8 + wave) * 1024 + mbase + ln15) * 512 + quad * 8;

    f32x4 acc[2][8] = {};

    #pragma unroll 4
    for (int ks = 0; ks < 16; ++ks) {
        const int k0 = ks * 32;
        bf16x8 aF[2], bF[8];
        #pragma unroll
        for (int i = 0; i < 2; ++i)
            aF[i] = *(const bf16x8*)(baseA + (size_t)(i * 16) * 512 + k0);
        #pragma unroll
        for (int j = 0; j < 8; ++j)
            bF[j] = *(const bf16x8*)(baseB + (size_t)(j * 16) * 512 + k0);

        #pragma unroll
        for (int i = 0; i < 2; ++i)
            #pragma unroll
            for (int j = 0; j < 8; ++j)
                acc[i][j] = __builtin_amdgcn_mfma_f32_16x16x32_bf16(
                    aF[i], bF[j], acc[i][j], 0, 0, 0);
    }

    // ---- epilogue: LDS transpose to c-contiguous, full-line writes (R12 verified) ----
    const float* aw = sums + (size_t)(b * 8 + wave) * 1024;
    const float* bw = sums + 16384 + (size_t)(b * 8 + wave) * 1024;
    float av[2][4];
    #pragma unroll
    for (int i = 0; i < 2; ++i)
        #pragma unroll
        for (int r = 0; r < 4; ++r)
            av[i][r] = aw[lbase + i * 16 + quad * 4 + r];
    float bv[8];
    #pragma unroll
    for (int j = 0; j < 8; ++j)
        bv[j] = bw[mbase + j * 16 + ln15];

    const int RS = 1153;
    #pragma unroll
    for (int i = 0; i < 2; ++i) {
        __syncthreads();              // prior chunk reads done (no-op cost, chunk 0)
        #pragma unroll
        for (int j = 0; j < 8; ++j)
            #pragma unroll
            for (int r = 0; r < 4; ++r)
                smE[(quad * 4 + r) * RS + (j * 16 + ln15) * 9 + wave] =
                    acc[i][j][r] + av[i][r] + bv[j];
        __syncthreads();
        #pragma unroll
        for (int rr2 = 0; rr2 < 2; ++rr2) {
            const int lr = rr2 * 8 + wave;
            const int l  = lbase + i * 16 + lr;
            const int e0 = lr * RS + (2 * lane) * 9;
            const int e1 = e0 + 9;
            float4 o0, o1, o2, o3;
            o0.x = smE[e0 + 0]; o0.y = smE[e0 + 1]; o0.z = smE[e0 + 2]; o0.w = smE[e0 + 3];
            o1.x = smE[e0 + 4]; o1.y = smE[e0 + 5]; o1.z = smE[e0 + 6]; o1.w = smE[e0 + 7];
            o2.x = smE[e1 + 0]; o2.y = smE[e1 + 1]; o2.z = smE[e1 + 2]; o2.w = smE[e1 + 3];
            o3.x = smE[e1 + 4]; o3.y = smE[e1 + 5]; o3.z = smE[e1 + 6]; o3.w = smE[e1 + 7];
            float* po = out + ((size_t)(b * 1024 + l) * 1024 + mbase) * 8 + lane * 16;
            *(float4*)(po)      = o0;
            *(float4*)(po + 4)  = o1;
            *(float4*)(po + 8)  = o2;
            *(float4*)(po + 12) = o3;
        }
    }
}

// ======================= FALLBACK PATH (round-10 verified, unchanged) =======================
__global__ __launch_bounds__(256) void sums_k(const float* __restrict__ sh,
                                              const float* __restrict__ eh,
                                              const float* __restrict__ v,
                                              float* __restrict__ ws) {
    const int gid  = blockIdx.x * 256 + threadIdx.x;
    const int row  = gid >> 6;
    const int lane = gid & 63;
    const int h    = lane * 8;

    const float* ps = sh + (size_t)row * 512 + h;
    const float* pe = eh + (size_t)row * 512 + h;
    float4 s0 = *(const float4*)ps;       float4 s1 = *(const float4*)(ps + 4);
    float4 e0 = *(const float4*)pe;       float4 e1 = *(const float4*)(pe + 4);
    float4 v10 = *(const float4*)(v + h);        float4 v11 = *(const float4*)(v + h + 4);
    float4 v20 = *(const float4*)(v + 512 + h);  float4 v21 = *(const float4*)(v + 512 + h + 4);
    float4 v30 = *(const float4*)(v + 1024 + h); float4 v31 = *(const float4*)(v + 1024 + h + 4);

    float da = s0.x*(v10.x+v30.x) + s0.y*(v10.y+v30.y) + s0.z*(v10.z+v30.z) + s0.w*(v10.w+v30.w)
             + s1.x*(v11.x+v31.x) + s1.y*(v11.y+v31.y) + s1.z*(v11.z+v31.z) + s1.w*(v11.w+v31.w);
    float db = e0.x*(v20.x-v30.x) + e0.y*(v20.y-v30.y) + e0.z*(v20.z-v30.z) + e0.w*(v20.w-v30.w)
             + e1.x*(v21.x-v31.x) + e1.y*(v21.y-v31.y) + e1.z*(v21.z-v31.z) + e1.w*(v21.w-v31.w);

    #pragma unroll
    for (int off = 32; off >= 1; off >>= 1) {
        da += __shfl_down(da, off, 64);
        db += __shfl_down(db, off, 64);
    }
    if (lane == 0) {
        ws[row]         = da;
        ws[16384 + row] = db;
    }
}

__global__ __launch_bounds__(512, 2) void gemm_k(const float* __restrict__ sh,
                                                 const float* __restrict__ eh,
                                                 const float* __restrict__ v,
                                                 const float* __restrict__ ws,
                                                 float* __restrict__ out) {
    __shared__ __align__(16) unsigned short smem[8 * 192 * 40];

    const int t    = threadIdx.x;
    const int bid  = blockIdx.x;
    const int b    = bid >> 7;
    const int lt   = (bid >> 3) & 15;
    const int mt   = bid & 7;
    const int lbase = lt * 64, mbase = mt * 128;

    const int lane = t & 63, wave = t >> 6;
    const int ln15 = lane & 15, quad = lane >> 4;

    const int k8 = lane & 3;
    const int rr = lane >> 2;

    const int wb = wave * 192;

    const float* baseA = sh + ((size_t)(b * 8 + wave) * 1024 + lbase) * 512;
    const float* baseB = eh + ((size_t)(b * 8 + wave) * 1024 + mbase) * 512;

    f32x4 acc[4][8] = {};

    for (int ks = 0; ks < 16; ++ks) {
        const int k0 = ks * 32 + k8 * 8;
        float4 w0 = *(const float4*)(v + 1536 + k0);
        float4 w1 = *(const float4*)(v + 1536 + k0 + 4);

        float4 xa[4][2], xb[8][2];
        #pragma unroll
        for (int s = 0; s < 4; ++s) {
            const float* p = baseA + (size_t)(s * 16 + rr) * 512 + k0;
            xa[s][0] = *(const float4*)p;  xa[s][1] = *(const float4*)(p + 4);
        }
        #pragma unroll
        for (int s = 0; s < 8; ++s) {
            const float* p = baseB + (size_t)(s * 16 + rr) * 512 + k0;
            xb[s][0] = *(const float4*)p;  xb[s][1] = *(const float4*)(p + 4);
        }

        #pragma unroll
        for (int s = 0; s < 4; ++s) {
            float4 a0 = xa[s][0], a1 = xa[s][1];
            a0.x *= w0.x; a0.y *= w0.y; a0.z *= w0.z; a0.w *= w0.w;
            a1.x *= w1.x; a1.y *= w1.y; a1.z *= w1.z; a1.w *= w1.w;
            *(uint4*)&smem[(wb + s * 16 + rr) * 40 + k8 * 8] = pack8(a0, a1);
        }
        #pragma unroll
        for (int s = 0; s < 8; ++s)
            *(uint4*)&smem[(wb + 64 + s * 16 + rr) * 40 + k8 * 8] = pack8(xb[s][0], xb[s][1]);

        bf16x8 aF[4], bF[8];
        #pragma unroll
        for (int i = 0; i < 4; ++i)
            aF[i] = *(const bf16x8*)&smem[(wb + i * 16 + ln15) * 40 + quad * 8];
        #pragma unroll
        for (int j = 0; j < 8; ++j)
            bF[j] = *(const bf16x8*)&smem[(wb + 64 + j * 16 + ln15) * 40 + quad * 8];
        #pragma unroll
        for (int i = 0; i < 4; ++i)
            #pragma unroll
            for (int j = 0; j < 8; ++j)
                acc[i][j] = __builtin_amdgcn_mfma_f32_16x16x32_bf16(
                    aF[i], bF[j], acc[i][j], 0, 0, 0);
    }

    const float* aw = ws + (size_t)(b * 8 + wave) * 1024;
    const float* bw = ws + 16384 + (size_t)(b * 8 + wave) * 1024;
    float av[4][4], bv[8];
    #pragma unroll
    for (int i = 0; i < 4; ++i)
        #pragma unroll
        for (int r = 0; r < 4; ++r)
            av[i][r] = aw[lbase + i * 16 + quad * 4 + r];
    #pragma unroll
    for (int j = 0; j < 8; ++j)
        bv[j] = bw[mbase + j * 16 + ln15];

    float* smE2 = (float*)smem;
    const int RS = 1153;
    #pragma unroll
    for (int i = 0; i < 4; ++i) {
        __syncthreads();
        #pragma unroll
        for (int j = 0; j < 8; ++j)
            #pragma unroll
            for (int r = 0; r < 4; ++r)
                smE2[(quad * 4 + r) * RS + (j * 16 + ln15) * 9 + wave] =
                    acc[i][j][r] + av[i][r] + bv[j];
        __syncthreads();
        #pragma unroll
        for (int rr2 = 0; rr2 < 2; ++rr2) {
            const int lr = rr2 * 8 + wave;
            const int l  = lbase + i * 16 + lr;
            const int e0 = lr * RS + (2 * lane) * 9;
            const int e1 = e0 + 9;
            float4 o0, o1, o2, o3;
            o0.x = smE2[e0 + 0]; o0.y = smE2[e0 + 1]; o0.z = smE2[e0 + 2]; o0.w = smE2[e0 + 3];
            o1.x = smE2[e0 + 4]; o1.y = smE2[e0 + 5]; o1.z = smE2[e0 + 6]; o1.w = smE2[e0 + 7];
            o2.x = smE2[e1 + 0]; o2.y = smE2[e1 + 1]; o2.z = smE2[e1 + 2]; o2.w = smE2[e1 + 3];
            o3.x = smE2[e1 + 4]; o3.y = smE2[e1 + 5]; o3.z = smE2[e1 + 6]; o3.w = smE2[e1 + 7];
            float* po = out + ((size_t)(b * 1024 + l) * 1024 + mbase) * 8 + lane * 16;
            *(float4*)(po)      = o0;
            *(float4*)(po + 4)  = o1;
            *(float4*)(po + 8)  = o2;
            *(float4*)(po + 12) = o3;
        }
    }
}

extern "C" void kernel_launch(void* const* d_in, const int* in_sizes, int n_in,
                              void* d_out, int out_size, void* d_ws, size_t ws_size,
                              hipStream_t stream) {
    (void)in_sizes; (void)n_in; (void)out_size;
    const float* sh = (const float*)d_in[0];
    const float* eh = (const float*)d_in[1];
    const float* v  = (const float*)d_in[2];
    float* out = (float*)d_out;

    const size_t need = 32768 * sizeof(float)
                      + 2 * (size_t)16384 * 512 * sizeof(unsigned short); // 33,685,504 B
    if (ws_size >= need) {
        float* sums = (float*)d_ws;
        unsigned short* Aw = (unsigned short*)((char*)d_ws + 32768 * sizeof(float));
        unsigned short* Bw = Aw + (size_t)16384 * 512;
        prep_k<<<4096, 256, 0, stream>>>(sh, eh, v, sums, Aw, Bw);
        gemm3_k<<<512, 512, 0, stream>>>(Aw, Bw, sums, out);
    } else {
        float* ws = (float*)d_ws;   // 32768 floats = 128 KB
        sums_k<<<4096, 256, 0, stream>>>(sh, eh, v, ws);
        gemm_k<<<256, 512, 0, stream>>>(sh, eh, v, ws, out);
    }
}

// Round 14
// 196.099 us; speedup vs baseline: 1.0459x; 1.0459x over previous
//
#include <hip/hip_runtime.h>
#include <hip/hip_bf16.h>

// B=2, C=8, L=1024, H=512
// out[((b*1024+l)*1024+m)*8 + c] = a[b,c,l] + bb[b,c,m] + sum_h start*v4*end
//
// Round 14: explicit software pipeline on the LDS-free K-loop.
//  - prep_k (verified): bf16 pre-pack, v4 folded into A, row dots.
//  - gemm4_k: 64l x 128m x 8c (grid 256 = 1 block/CU), wave = c-plane,
//    fragments loaded DIRECTLY from global; hand-unrolled x2 with two NAMED
//    register buffer sets (depth-1 prefetch); __launch_bounds__(512,2) grants
//    the VGPR budget R13's compiler heuristic withheld (VGPR 68 -> ~220).
//    No barriers in the K-loop. Epilogue = R10-verified 4-chunk LDS transpose.
// Fallback path (ws too small): round-10 verified kernels unchanged.

typedef short bf16x8 __attribute__((ext_vector_type(8)));
typedef float f32x4 __attribute__((ext_vector_type(4)));

__device__ __forceinline__ unsigned short f2bf(float x) {
    unsigned int u = __float_as_uint(x);
    u += 0x7fffu + ((u >> 16) & 1u);   // round-to-nearest-even
    return (unsigned short)(u >> 16);
}

__device__ __forceinline__ uint4 pack8(float4 a, float4 b) {
    uint4 r;
    r.x = (unsigned)f2bf(a.x) | ((unsigned)f2bf(a.y) << 16);
    r.y = (unsigned)f2bf(a.z) | ((unsigned)f2bf(a.w) << 16);
    r.z = (unsigned)f2bf(b.x) | ((unsigned)f2bf(b.y) << 16);
    r.w = (unsigned)f2bf(b.z) | ((unsigned)f2bf(b.w) << 16);
    return r;
}

// ---------------- prep: row dots + bf16 conversion (R11 verified, unchanged) ----------------
__global__ __launch_bounds__(256) void prep_k(const float* __restrict__ sh,
                                              const float* __restrict__ eh,
                                              const float* __restrict__ v,
                                              float* __restrict__ sums,
                                              unsigned short* __restrict__ Aw,
                                              unsigned short* __restrict__ Bw) {
    const int gid  = blockIdx.x * 256 + threadIdx.x;
    const int row  = gid >> 6;
    const int lane = gid & 63;
    const int h    = lane * 8;

    const float* ps = sh + (size_t)row * 512 + h;
    const float* pe = eh + (size_t)row * 512 + h;
    float4 s0 = *(const float4*)ps;       float4 s1 = *(const float4*)(ps + 4);
    float4 e0 = *(const float4*)pe;       float4 e1 = *(const float4*)(pe + 4);
    float4 v10 = *(const float4*)(v + h);        float4 v11 = *(const float4*)(v + h + 4);
    float4 v20 = *(const float4*)(v + 512 + h);  float4 v21 = *(const float4*)(v + 512 + h + 4);
    float4 v30 = *(const float4*)(v + 1024 + h); float4 v31 = *(const float4*)(v + 1024 + h + 4);
    float4 v40 = *(const float4*)(v + 1536 + h); float4 v41 = *(const float4*)(v + 1536 + h + 4);

    float da = s0.x*(v10.x+v30.x) + s0.y*(v10.y+v30.y) + s0.z*(v10.z+v30.z) + s0.w*(v10.w+v30.w)
             + s1.x*(v11.x+v31.x) + s1.y*(v11.y+v31.y) + s1.z*(v11.z+v31.z) + s1.w*(v11.w+v31.w);
    float db = e0.x*(v20.x-v30.x) + e0.y*(v20.y-v30.y) + e0.z*(v20.z-v30.z) + e0.w*(v20.w-v30.w)
             + e1.x*(v21.x-v31.x) + e1.y*(v21.y-v31.y) + e1.z*(v21.z-v31.z) + e1.w*(v21.w-v31.w);

    float4 a0 = s0, a1 = s1;
    a0.x *= v40.x; a0.y *= v40.y; a0.z *= v40.z; a0.w *= v40.w;
    a1.x *= v41.x; a1.y *= v41.y; a1.z *= v41.z; a1.w *= v41.w;
    *(uint4*)&Aw[(size_t)row * 512 + h] = pack8(a0, a1);
    *(uint4*)&Bw[(size_t)row * 512 + h] = pack8(e0, e1);

    #pragma unroll
    for (int off = 32; off >= 1; off >>= 1) {
        da += __shfl_down(da, off, 64);
        db += __shfl_down(db, off, 64);
    }
    if (lane == 0) {
        sums[row]         = da;
        sums[16384 + row] = db;
    }
}

// ---------------- gemm4: LDS-free K-loop, explicit depth-1 prefetch ----------------
// grid 256: bid = lt*16 + b*8 + mt  (bid%8 = mt -> B-panel users share an XCD)
__global__ __launch_bounds__(512, 2) void gemm4_k(const unsigned short* __restrict__ Aw,
                                                  const unsigned short* __restrict__ Bw,
                                                  const float* __restrict__ sums,
                                                  float* __restrict__ out) {
    // LDS: epilogue transpose scratch only (16 rows x 1153 floats = 73.8 KB)
    __shared__ __align__(16) float smE[16 * 1153];

    const int t    = threadIdx.x;
    const int bid  = blockIdx.x;
    const int mt   = bid & 7;
    const int b    = (bid >> 3) & 1;
    const int lt   = bid >> 4;            // 0..15
    const int lbase = lt * 64, mbase = mt * 128;

    const int lane = t & 63, wave = t >> 6;   // wave = c-plane (0..7)
    const int ln15 = lane & 15, quad = lane >> 4;

    // per-lane fragment base: row ln15 (within 16-row group), k-block quad
    const unsigned short* baseA =
        Aw + ((size_t)(b * 8 + wave) * 1024 + lbase + ln15) * 512 + quad * 8;
    const unsigned short* baseB =
        Bw + ((size_t)(b * 8 + wave) * 1024 + mbase + ln15) * 512 + quad * 8;

    f32x4 acc[4][8] = {};

    bf16x8 pa[4], pb[8], qa[4], qb[8];    // two named fragment buffers

    auto LOADP = [&](int ks) {
        const int k0 = ks * 32;
        #pragma unroll
        for (int i = 0; i < 4; ++i)
            pa[i] = *(const bf16x8*)(baseA + (size_t)(i * 16) * 512 + k0);
        #pragma unroll
        for (int j = 0; j < 8; ++j)
            pb[j] = *(const bf16x8*)(baseB + (size_t)(j * 16) * 512 + k0);
    };
    auto LOADQ = [&](int ks) {
        const int k0 = ks * 32;
        #pragma unroll
        for (int i = 0; i < 4; ++i)
            qa[i] = *(const bf16x8*)(baseA + (size_t)(i * 16) * 512 + k0);
        #pragma unroll
        for (int j = 0; j < 8; ++j)
            qb[j] = *(const bf16x8*)(baseB + (size_t)(j * 16) * 512 + k0);
    };
    auto MFMAP = [&]() {
        #pragma unroll
        for (int i = 0; i < 4; ++i)
            #pragma unroll
            for (int j = 0; j < 8; ++j)
                acc[i][j] = __builtin_amdgcn_mfma_f32_16x16x32_bf16(pa[i], pb[j], acc[i][j], 0, 0, 0);
    };
    auto MFMAQ = [&]() {
        #pragma unroll
        for (int i = 0; i < 4; ++i)
            #pragma unroll
            for (int j = 0; j < 8; ++j)
                acc[i][j] = __builtin_amdgcn_mfma_f32_16x16x32_bf16(qa[i], qb[j], acc[i][j], 0, 0, 0);
    };

    // software pipeline, depth 1: loads for step n+1 issue before MFMAs of step n
    LOADP(0);
    #pragma unroll
    for (int ks = 0; ks < 14; ks += 2) {
        LOADQ(ks + 1);
        MFMAP();
        LOADP(ks + 2);
        MFMAQ();
    }
    LOADQ(15);
    MFMAP();      // ks = 14
    MFMAQ();      // ks = 15

    // ---- epilogue: LDS transpose to c-contiguous, full-line writes (R10 verified) ----
    const float* aw = sums + (size_t)(b * 8 + wave) * 1024;
    const float* bw = sums + 16384 + (size_t)(b * 8 + wave) * 1024;
    float av[4][4], bv[8];
    #pragma unroll
    for (int i = 0; i < 4; ++i)
        #pragma unroll
        for (int r = 0; r < 4; ++r)
            av[i][r] = aw[lbase + i * 16 + quad * 4 + r];
    #pragma unroll
    for (int j = 0; j < 8; ++j)
        bv[j] = bw[mbase + j * 16 + ln15];

    const int RS = 1153;
    #pragma unroll
    for (int i = 0; i < 4; ++i) {     // 4 chunks of 16 l-rows
        __syncthreads();
        #pragma unroll
        for (int j = 0; j < 8; ++j)
            #pragma unroll
            for (int r = 0; r < 4; ++r)
                smE[(quad * 4 + r) * RS + (j * 16 + ln15) * 9 + wave] =
                    acc[i][j][r] + av[i][r] + bv[j];
        __syncthreads();
        #pragma unroll
        for (int rr2 = 0; rr2 < 2; ++rr2) {
            const int lr = rr2 * 8 + wave;
            const int l  = lbase + i * 16 + lr;
            const int e0 = lr * RS + (2 * lane) * 9;
            const int e1 = e0 + 9;
            float4 o0, o1, o2, o3;
            o0.x = smE[e0 + 0]; o0.y = smE[e0 + 1]; o0.z = smE[e0 + 2]; o0.w = smE[e0 + 3];
            o1.x = smE[e0 + 4]; o1.y = smE[e0 + 5]; o1.z = smE[e0 + 6]; o1.w = smE[e0 + 7];
            o2.x = smE[e1 + 0]; o2.y = smE[e1 + 1]; o2.z = smE[e1 + 2]; o2.w = smE[e1 + 3];
            o3.x = smE[e1 + 4]; o3.y = smE[e1 + 5]; o3.z = smE[e1 + 6]; o3.w = smE[e1 + 7];
            float* po = out + ((size_t)(b * 1024 + l) * 1024 + mbase) * 8 + lane * 16;
            *(float4*)(po)      = o0;
            *(float4*)(po + 4)  = o1;
            *(float4*)(po + 8)  = o2;
            *(float4*)(po + 12) = o3;
        }
    }
}

// ======================= FALLBACK PATH (round-10 verified, unchanged) =======================
__global__ __launch_bounds__(256) void sums_k(const float* __restrict__ sh,
                                              const float* __restrict__ eh,
                                              const float* __restrict__ v,
                                              float* __restrict__ ws) {
    const int gid  = blockIdx.x * 256 + threadIdx.x;
    const int row  = gid >> 6;
    const int lane = gid & 63;
    const int h    = lane * 8;

    const float* ps = sh + (size_t)row * 512 + h;
    const float* pe = eh + (size_t)row * 512 + h;
    float4 s0 = *(const float4*)ps;       float4 s1 = *(const float4*)(ps + 4);
    float4 e0 = *(const float4*)pe;       float4 e1 = *(const float4*)(pe + 4);
    float4 v10 = *(const float4*)(v + h);        float4 v11 = *(const float4*)(v + h + 4);
    float4 v20 = *(const float4*)(v + 512 + h);  float4 v21 = *(const float4*)(v + 512 + h + 4);
    float4 v30 = *(const float4*)(v + 1024 + h); float4 v31 = *(const float4*)(v + 1024 + h + 4);

    float da = s0.x*(v10.x+v30.x) + s0.y*(v10.y+v30.y) + s0.z*(v10.z+v30.z) + s0.w*(v10.w+v30.w)
             + s1.x*(v11.x+v31.x) + s1.y*(v11.y+v31.y) + s1.z*(v11.z+v31.z) + s1.w*(v11.w+v31.w);
    float db = e0.x*(v20.x-v30.x) + e0.y*(v20.y-v30.y) + e0.z*(v20.z-v30.z) + e0.w*(v20.w-v30.w)
             + e1.x*(v21.x-v31.x) + e1.y*(v21.y-v31.y) + e1.z*(v21.z-v31.z) + e1.w*(v21.w-v31.w);

    #pragma unroll
    for (int off = 32; off >= 1; off >>= 1) {
        da += __shfl_down(da, off, 64);
        db += __shfl_down(db, off, 64);
    }
    if (lane == 0) {
        ws[row]         = da;
        ws[16384 + row] = db;
    }
}

__global__ __launch_bounds__(512, 2) void gemm_k(const float* __restrict__ sh,
                                                 const float* __restrict__ eh,
                                                 const float* __restrict__ v,
                                                 const float* __restrict__ ws,
                                                 float* __restrict__ out) {
    __shared__ __align__(16) unsigned short smem[8 * 192 * 40];

    const int t    = threadIdx.x;
    const int bid  = blockIdx.x;
    const int b    = bid >> 7;
    const int lt   = (bid >> 3) & 15;
    const int mt   = bid & 7;
    const int lbase = lt * 64, mbase = mt * 128;

    const int lane = t & 63, wave = t >> 6;
    const int ln15 = lane & 15, quad = lane >> 4;

    const int k8 = lane & 3;
    const int rr = lane >> 2;

    const int wb = wave * 192;

    const float* baseA = sh + ((size_t)(b * 8 + wave) * 1024 + lbase) * 512;
    const float* baseB = eh + ((size_t)(b * 8 + wave) * 1024 + mbase) * 512;

    f32x4 acc[4][8] = {};

    for (int ks = 0; ks < 16; ++ks) {
        const int k0 = ks * 32 + k8 * 8;
        float4 w0 = *(const float4*)(v + 1536 + k0);
        float4 w1 = *(const float4*)(v + 1536 + k0 + 4);

        float4 xa[4][2], xb[8][2];
        #pragma unroll
        for (int s = 0; s < 4; ++s) {
            const float* p = baseA + (size_t)(s * 16 + rr) * 512 + k0;
            xa[s][0] = *(const float4*)p;  xa[s][1] = *(const float4*)(p + 4);
        }
        #pragma unroll
        for (int s = 0; s < 8; ++s) {
            const float* p = baseB + (size_t)(s * 16 + rr) * 512 + k0;
            xb[s][0] = *(const float4*)p;  xb[s][1] = *(const float4*)(p + 4);
        }

        #pragma unroll
        for (int s = 0; s < 4; ++s) {
            float4 a0 = xa[s][0], a1 = xa[s][1];
            a0.x *= w0.x; a0.y *= w0.y; a0.z *= w0.z; a0.w *= w0.w;
            a1.x *= w1.x; a1.y *= w1.y; a1.z *= w1.z; a1.w *= w1.w;
            *(uint4*)&smem[(wb + s * 16 + rr) * 40 + k8 * 8] = pack8(a0, a1);
        }
        #pragma unroll
        for (int s = 0; s < 8; ++s)
            *(uint4*)&smem[(wb + 64 + s * 16 + rr) * 40 + k8 * 8] = pack8(xb[s][0], xb[s][1]);

        bf16x8 aF[4], bF[8];
        #pragma unroll
        for (int i = 0; i < 4; ++i)
            aF[i] = *(const bf16x8*)&smem[(wb + i * 16 + ln15) * 40 + quad * 8];
        #pragma unroll
        for (int j = 0; j < 8; ++j)
            bF[j] = *(const bf16x8*)&smem[(wb + 64 + j * 16 + ln15) * 40 + quad * 8];
        #pragma unroll
        for (int i = 0; i < 4; ++i)
            #pragma unroll
            for (int j = 0; j < 8; ++j)
                acc[i][j] = __builtin_amdgcn_mfma_f32_16x16x32_bf16(
                    aF[i], bF[j], acc[i][j], 0, 0, 0);
    }

    const float* aw = ws + (size_t)(b * 8 + wave) * 1024;
    const float* bw = ws + 16384 + (size_t)(b * 8 + wave) * 1024;
    float av[4][4], bv[8];
    #pragma unroll
    for (int i = 0; i < 4; ++i)
        #pragma unroll
        for (int r = 0; r < 4; ++r)
            av[i][r] = aw[lbase + i * 16 + quad * 4 + r];
    #pragma unroll
    for (int j = 0; j < 8; ++j)
        bv[j] = bw[mbase + j * 16 + ln15];

    float* smE2 = (float*)smem;
    const int RS = 1153;
    #pragma unroll
    for (int i = 0; i < 4; ++i) {
        __syncthreads();
        #pragma unroll
        for (int j = 0; j < 8; ++j)
            #pragma unroll
            for (int r = 0; r < 4; ++r)
                smE2[(quad * 4 + r) * RS + (j * 16 + ln15) * 9 + wave] =
                    acc[i][j][r] + av[i][r] + bv[j];
        __syncthreads();
        #pragma unroll
        for (int rr2 = 0; rr2 < 2; ++rr2) {
            const int lr = rr2 * 8 + wave;
            const int l  = lbase + i * 16 + lr;
            const int e0 = lr * RS + (2 * lane) * 9;
            const int e1 = e0 + 9;
            float4 o0, o1, o2, o3;
            o0.x = smE2[e0 + 0]; o0.y = smE2[e0 + 1]; o0.z = smE2[e0 + 2]; o0.w = smE2[e0 + 3];
            o1.x = smE2[e0 + 4]; o1.y = smE2[e0 + 5]; o1.z = smE2[e0 + 6]; o1.w = smE2[e0 + 7];
            o2.x = smE2[e1 + 0]; o2.y = smE2[e1 + 1]; o2.z = smE2[e1 + 2]; o2.w = smE2[e1 + 3];
            o3.x = smE2[e1 + 4]; o3.y = smE2[e1 + 5]; o3.z = smE2[e1 + 6]; o3.w = smE2[e1 + 7];
            float* po = out + ((size_t)(b * 1024 + l) * 1024 + mbase) * 8 + lane * 16;
            *(float4*)(po)      = o0;
            *(float4*)(po + 4)  = o1;
            *(float4*)(po + 8)  = o2;
            *(float4*)(po + 12) = o3;
        }
    }
}

extern "C" void kernel_launch(void* const* d_in, const int* in_sizes, int n_in,
                              void* d_out, int out_size, void* d_ws, size_t ws_size,
                              hipStream_t stream) {
    (void)in_sizes; (void)n_in; (void)out_size;
    const float* sh = (const float*)d_in[0];
    const float* eh = (const float*)d_in[1];
    const float* v  = (const float*)d_in[2];
    float* out = (float*)d_out;

    const size_t need = 32768 * sizeof(float)
                      + 2 * (size_t)16384 * 512 * sizeof(unsigned short); // 33,685,504 B
    if (ws_size >= need) {
        float* sums = (float*)d_ws;
        unsigned short* Aw = (unsigned short*)((char*)d_ws + 32768 * sizeof(float));
        unsigned short* Bw = Aw + (size_t)16384 * 512;
        prep_k<<<4096, 256, 0, stream>>>(sh, eh, v, sums, Aw, Bw);
        gemm4_k<<<256, 512, 0, stream>>>(Aw, Bw, sums, out);
    } else {
        float* ws = (float*)d_ws;   // 32768 floats = 128 KB
        sums_k<<<4096, 256, 0, stream>>>(sh, eh, v, ws);
        gemm_k<<<256, 512, 0, stream>>>(sh, eh, v, ws, out);
    }
}

// Round 15
// 160.021 us; speedup vs baseline: 1.2818x; 1.2255x over previous
//
#include <hip/hip_runtime.h>
#include <hip/hip_bf16.h>

// B=2, C=8, L=1024, H=512
// out[((b*1024+l)*1024+m)*8 + c] = a[b,c,l] + bb[b,c,m] + sum_h start*v4*end
//
// Round 15: back to the R11-verified structure (gload_lds staging + drain),
// with the ONE change its counters motivate: tile 64l x 64m x 8c -> 64 KB LDS
// -> 2 blocks/CU -> 4 waves/SIMD (R11: 147KB, 1 block/CU, 2 waves/SIMD).
// Staging groups/swizzle/frag formulas identical to R11 (verified). Epilogue =
// verified transpose, readout simplified to one m per lane (RS=577).
// prep_k unchanged (verified). Fallback path: round-10 verified kernels.

typedef short bf16x8 __attribute__((ext_vector_type(8)));
typedef float f32x4 __attribute__((ext_vector_type(4)));

__device__ __forceinline__ unsigned short f2bf(float x) {
    unsigned int u = __float_as_uint(x);
    u += 0x7fffu + ((u >> 16) & 1u);   // round-to-nearest-even
    return (unsigned short)(u >> 16);
}

__device__ __forceinline__ uint4 pack8(float4 a, float4 b) {
    uint4 r;
    r.x = (unsigned)f2bf(a.x) | ((unsigned)f2bf(a.y) << 16);
    r.y = (unsigned)f2bf(a.z) | ((unsigned)f2bf(a.w) << 16);
    r.z = (unsigned)f2bf(b.x) | ((unsigned)f2bf(b.y) << 16);
    r.w = (unsigned)f2bf(b.z) | ((unsigned)f2bf(b.w) << 16);
    return r;
}

__device__ __forceinline__ void gload16(const unsigned short* g, unsigned short* l) {
    __builtin_amdgcn_global_load_lds(
        (const __attribute__((address_space(1))) unsigned int*)g,
        (__attribute__((address_space(3))) unsigned int*)l, 16, 0, 0);
}

// ---------------- prep: row dots + bf16 conversion (R11 verified, unchanged) ----------------
__global__ __launch_bounds__(256) void prep_k(const float* __restrict__ sh,
                                              const float* __restrict__ eh,
                                              const float* __restrict__ v,
                                              float* __restrict__ sums,
                                              unsigned short* __restrict__ Aw,
                                              unsigned short* __restrict__ Bw) {
    const int gid  = blockIdx.x * 256 + threadIdx.x;
    const int row  = gid >> 6;
    const int lane = gid & 63;
    const int h    = lane * 8;

    const float* ps = sh + (size_t)row * 512 + h;
    const float* pe = eh + (size_t)row * 512 + h;
    float4 s0 = *(const float4*)ps;       float4 s1 = *(const float4*)(ps + 4);
    float4 e0 = *(const float4*)pe;       float4 e1 = *(const float4*)(pe + 4);
    float4 v10 = *(const float4*)(v + h);        float4 v11 = *(const float4*)(v + h + 4);
    float4 v20 = *(const float4*)(v + 512 + h);  float4 v21 = *(const float4*)(v + 512 + h + 4);
    float4 v30 = *(const float4*)(v + 1024 + h); float4 v31 = *(const float4*)(v + 1024 + h + 4);
    float4 v40 = *(const float4*)(v + 1536 + h); float4 v41 = *(const float4*)(v + 1536 + h + 4);

    float da = s0.x*(v10.x+v30.x) + s0.y*(v10.y+v30.y) + s0.z*(v10.z+v30.z) + s0.w*(v10.w+v30.w)
             + s1.x*(v11.x+v31.x) + s1.y*(v11.y+v31.y) + s1.z*(v11.z+v31.z) + s1.w*(v11.w+v31.w);
    float db = e0.x*(v20.x-v30.x) + e0.y*(v20.y-v30.y) + e0.z*(v20.z-v30.z) + e0.w*(v20.w-v30.w)
             + e1.x*(v21.x-v31.x) + e1.y*(v21.y-v31.y) + e1.z*(v21.z-v31.z) + e1.w*(v21.w-v31.w);

    float4 a0 = s0, a1 = s1;
    a0.x *= v40.x; a0.y *= v40.y; a0.z *= v40.z; a0.w *= v40.w;
    a1.x *= v41.x; a1.y *= v41.y; a1.z *= v41.z; a1.w *= v41.w;
    *(uint4*)&Aw[(size_t)row * 512 + h] = pack8(a0, a1);
    *(uint4*)&Bw[(size_t)row * 512 + h] = pack8(e0, e1);

    #pragma unroll
    for (int off = 32; off >= 1; off >>= 1) {
        da += __shfl_down(da, off, 64);
        db += __shfl_down(db, off, 64);
    }
    if (lane == 0) {
        sums[row]         = da;
        sums[16384 + row] = db;
    }
}

// ---------------- gemm5: R11 staging structure, 64l x 64m x 8c, 2 blocks/CU ----------------
// grid 512: bid = lt*32 + b*16 + mt  (bid%8 tracks mt -> B-panel users share an XCD)
__global__ __launch_bounds__(512) void gemm5_k(const unsigned short* __restrict__ Aw,
                                               const unsigned short* __restrict__ Bw,
                                               const float* __restrict__ sums,
                                               float* __restrict__ out) {
    // per-wave region: 128 rows x 32 bf16 (64B): A rows 0..63, B rows 64..127.
    // 8 waves x 128 x 64B = 64 KB -> 2 blocks/CU. Epilogue aliases as float.
    __shared__ __align__(16) unsigned short smem[8 * 128 * 32];

    const int t    = threadIdx.x;
    const int bid  = blockIdx.x;
    const int mt   = bid & 15;
    const int b    = (bid >> 4) & 1;
    const int lt   = bid >> 5;            // 0..15
    const int lbase = lt * 64, mbase = mt * 64;

    const int lane = t & 63, wave = t >> 6;   // wave = c-plane (0..7)
    const int ln15 = lane & 15, quad = lane >> 4;

    const int rloc = lane >> 2;           // 0..15 row within a 16-row stage group
    const int slot = lane & 3;            // 16B slot within a 64B row
    const int kb   = slot ^ (rloc & 3);   // source-side XOR swizzle (R11 verified)

    const int wb = wave * 128;            // this wave's LDS row base

    const unsigned short* baseA = Aw + ((size_t)(b * 8 + wave) * 1024 + lbase) * 512;
    const unsigned short* baseB = Bw + ((size_t)(b * 8 + wave) * 1024 + mbase) * 512;

    f32x4 acc[4][4] = {};

    for (int ks = 0; ks < 16; ++ks) {
        const unsigned short* Ag = baseA + ks * 32;
        const unsigned short* Bg = baseB + ks * 32;

        // stage A (4 insts x 16 rows) and B (4 insts) into private LDS.
        #pragma unroll
        for (int s = 0; s < 4; ++s)
            gload16(Ag + (size_t)(s * 16 + rloc) * 512 + kb * 8,
                    &smem[(wb + s * 16) * 32]);
        #pragma unroll
        for (int s = 0; s < 4; ++s)
            gload16(Bg + (size_t)(s * 16 + rloc) * 512 + kb * 8,
                    &smem[(wb + 64 + s * 16) * 32]);

        asm volatile("s_waitcnt vmcnt(0)" ::: "memory");

        // frag reads: LDS[r][slot] holds global k-block slot^(r&3); invert on read.
        bf16x8 aF[4], bF[4];
        #pragma unroll
        for (int i = 0; i < 4; ++i)
            aF[i] = *(const bf16x8*)&smem[(wb + i * 16 + ln15) * 32 + ((quad ^ (ln15 & 3)) * 8)];
        #pragma unroll
        for (int j = 0; j < 4; ++j)
            bF[j] = *(const bf16x8*)&smem[(wb + 64 + j * 16 + ln15) * 32 + ((quad ^ (ln15 & 3)) * 8)];

        #pragma unroll
        for (int i = 0; i < 4; ++i)
            #pragma unroll
            for (int j = 0; j < 4; ++j)
                acc[i][j] = __builtin_amdgcn_mfma_f32_16x16x32_bf16(
                    aF[i], bF[j], acc[i][j], 0, 0, 0);
    }

    // ---- epilogue: LDS transpose to c-contiguous, full-line writes ----
    const float* aw = sums + (size_t)(b * 8 + wave) * 1024;
    const float* bw = sums + 16384 + (size_t)(b * 8 + wave) * 1024;
    float av[4][4];
    #pragma unroll
    for (int i = 0; i < 4; ++i)
        #pragma unroll
        for (int r = 0; r < 4; ++r)
            av[i][r] = aw[lbase + i * 16 + quad * 4 + r];
    float bv[4];
    #pragma unroll
    for (int j = 0; j < 4; ++j)
        bv[j] = bw[mbase + j * 16 + ln15];

    // chunk = 16 l-rows; per row 64 m x 9 slots (8 c + pad). RS=577 (odd).
    float* smE = (float*)smem;            // 16384 floats avail; need 16*577=9232
    const int RS = 577;
    #pragma unroll
    for (int i = 0; i < 4; ++i) {         // 4 chunks over 64 l-rows
        __syncthreads();                  // prior reads (K-loop or last chunk) done
        #pragma unroll
        for (int j = 0; j < 4; ++j)
            #pragma unroll
            for (int r = 0; r < 4; ++r)
                smE[(quad * 4 + r) * RS + (j * 16 + ln15) * 9 + wave] =
                    acc[i][j][r] + av[i][r] + bv[j];
        __syncthreads();
        // readout: wave handles chunk-rows {wave, 8+wave}; one m per lane (8 c)
        #pragma unroll
        for (int rr2 = 0; rr2 < 2; ++rr2) {
            const int lr = rr2 * 8 + wave;
            const int l  = lbase + i * 16 + lr;
            const int e0 = lr * RS + lane * 9;
            float4 o0, o1;
            o0.x = smE[e0 + 0]; o0.y = smE[e0 + 1]; o0.z = smE[e0 + 2]; o0.w = smE[e0 + 3];
            o1.x = smE[e0 + 4]; o1.y = smE[e0 + 5]; o1.z = smE[e0 + 6]; o1.w = smE[e0 + 7];
            float* po = out + ((size_t)(b * 1024 + l) * 1024 + mbase) * 8 + lane * 8;
            *(float4*)(po)     = o0;
            *(float4*)(po + 4) = o1;
        }
    }
}

// ======================= FALLBACK PATH (round-10 verified, unchanged) =======================
__global__ __launch_bounds__(256) void sums_k(const float* __restrict__ sh,
                                              const float* __restrict__ eh,
                                              const float* __restrict__ v,
                                              float* __restrict__ ws) {
    const int gid  = blockIdx.x * 256 + threadIdx.x;
    const int row  = gid >> 6;
    const int lane = gid & 63;
    const int h    = lane * 8;

    const float* ps = sh + (size_t)row * 512 + h;
    const float* pe = eh + (size_t)row * 512 + h;
    float4 s0 = *(const float4*)ps;       float4 s1 = *(const float4*)(ps + 4);
    float4 e0 = *(const float4*)pe;       float4 e1 = *(const float4*)(pe + 4);
    float4 v10 = *(const float4*)(v + h);        float4 v11 = *(const float4*)(v + h + 4);
    float4 v20 = *(const float4*)(v + 512 + h);  float4 v21 = *(const float4*)(v + 512 + h + 4);
    float4 v30 = *(const float4*)(v + 1024 + h); float4 v31 = *(const float4*)(v + 1024 + h + 4);

    float da = s0.x*(v10.x+v30.x) + s0.y*(v10.y+v30.y) + s0.z*(v10.z+v30.z) + s0.w*(v10.w+v30.w)
             + s1.x*(v11.x+v31.x) + s1.y*(v11.y+v31.y) + s1.z*(v11.z+v31.z) + s1.w*(v11.w+v31.w);
    float db = e0.x*(v20.x-v30.x) + e0.y*(v20.y-v30.y) + e0.z*(v20.z-v30.z) + e0.w*(v20.w-v30.w)
             + e1.x*(v21.x-v31.x) + e1.y*(v21.y-v31.y) + e1.z*(v21.z-v31.z) + e1.w*(v21.w-v31.w);

    #pragma unroll
    for (int off = 32; off >= 1; off >>= 1) {
        da += __shfl_down(da, off, 64);
        db += __shfl_down(db, off, 64);
    }
    if (lane == 0) {
        ws[row]         = da;
        ws[16384 + row] = db;
    }
}

__global__ __launch_bounds__(512, 2) void gemm_k(const float* __restrict__ sh,
                                                 const float* __restrict__ eh,
                                                 const float* __restrict__ v,
                                                 const float* __restrict__ ws,
                                                 float* __restrict__ out) {
    __shared__ __align__(16) unsigned short smem[8 * 192 * 40];

    const int t    = threadIdx.x;
    const int bid  = blockIdx.x;
    const int b    = bid >> 7;
    const int lt   = (bid >> 3) & 15;
    const int mt   = bid & 7;
    const int lbase = lt * 64, mbase = mt * 128;

    const int lane = t & 63, wave = t >> 6;
    const int ln15 = lane & 15, quad = lane >> 4;

    const int k8 = lane & 3;
    const int rr = lane >> 2;

    const int wb = wave * 192;

    const float* baseA = sh + ((size_t)(b * 8 + wave) * 1024 + lbase) * 512;
    const float* baseB = eh + ((size_t)(b * 8 + wave) * 1024 + mbase) * 512;

    f32x4 acc[4][8] = {};

    for (int ks = 0; ks < 16; ++ks) {
        const int k0 = ks * 32 + k8 * 8;
        float4 w0 = *(const float4*)(v + 1536 + k0);
        float4 w1 = *(const float4*)(v + 1536 + k0 + 4);

        float4 xa[4][2], xb[8][2];
        #pragma unroll
        for (int s = 0; s < 4; ++s) {
            const float* p = baseA + (size_t)(s * 16 + rr) * 512 + k0;
            xa[s][0] = *(const float4*)p;  xa[s][1] = *(const float4*)(p + 4);
        }
        #pragma unroll
        for (int s = 0; s < 8; ++s) {
            const float* p = baseB + (size_t)(s * 16 + rr) * 512 + k0;
            xb[s][0] = *(const float4*)p;  xb[s][1] = *(const float4*)(p + 4);
        }

        #pragma unroll
        for (int s = 0; s < 4; ++s) {
            float4 a0 = xa[s][0], a1 = xa[s][1];
            a0.x *= w0.x; a0.y *= w0.y; a0.z *= w0.z; a0.w *= w0.w;
            a1.x *= w1.x; a1.y *= w1.y; a1.z *= w1.z; a1.w *= w1.w;
            *(uint4*)&smem[(wb + s * 16 + rr) * 40 + k8 * 8] = pack8(a0, a1);
        }
        #pragma unroll
        for (int s = 0; s < 8; ++s)
            *(uint4*)&smem[(wb + 64 + s * 16 + rr) * 40 + k8 * 8] = pack8(xb[s][0], xb[s][1]);

        bf16x8 aF[4], bF[8];
        #pragma unroll
        for (int i = 0; i < 4; ++i)
            aF[i] = *(const bf16x8*)&smem[(wb + i * 16 + ln15) * 40 + quad * 8];
        #pragma unroll
        for (int j = 0; j < 8; ++j)
            bF[j] = *(const bf16x8*)&smem[(wb + 64 + j * 16 + ln15) * 40 + quad * 8];
        #pragma unroll
        for (int i = 0; i < 4; ++i)
            #pragma unroll
            for (int j = 0; j < 8; ++j)
                acc[i][j] = __builtin_amdgcn_mfma_f32_16x16x32_bf16(
                    aF[i], bF[j], acc[i][j], 0, 0, 0);
    }

    const float* aw = ws + (size_t)(b * 8 + wave) * 1024;
    const float* bw = ws + 16384 + (size_t)(b * 8 + wave) * 1024;
    float av[4][4], bv[8];
    #pragma unroll
    for (int i = 0; i < 4; ++i)
        #pragma unroll
        for (int r = 0; r < 4; ++r)
            av[i][r] = aw[lbase + i * 16 + quad * 4 + r];
    #pragma unroll
    for (int j = 0; j < 8; ++j)
        bv[j] = bw[mbase + j * 16 + ln15];

    float* smE2 = (float*)smem;
    const int RS = 1153;
    #pragma unroll
    for (int i = 0; i < 4; ++i) {
        __syncthreads();
        #pragma unroll
        for (int j = 0; j < 8; ++j)
            #pragma unroll
            for (int r = 0; r < 4; ++r)
                smE2[(quad * 4 + r) * RS + (j * 16 + ln15) * 9 + wave] =
                    acc[i][j][r] + av[i][r] + bv[j];
        __syncthreads();
        #pragma unroll
        for (int rr2 = 0; rr2 < 2; ++rr2) {
            const int lr = rr2 * 8 + wave;
            const int l  = lbase + i * 16 + lr;
            const int e0 = lr * RS + (2 * lane) * 9;
            const int e1 = e0 + 9;
            float4 o0, o1, o2, o3;
            o0.x = smE2[e0 + 0]; o0.y = smE2[e0 + 1]; o0.z = smE2[e0 + 2]; o0.w = smE2[e0 + 3];
            o1.x = smE2[e0 + 4]; o1.y = smE2[e0 + 5]; o1.z = smE2[e0 + 6]; o1.w = smE2[e0 + 7];
            o2.x = smE2[e1 + 0]; o2.y = smE2[e1 + 1]; o2.z = smE2[e1 + 2]; o2.w = smE2[e1 + 3];
            o3.x = smE2[e1 + 4]; o3.y = smE2[e1 + 5]; o3.z = smE2[e1 + 6]; o3.w = smE2[e1 + 7];
            float* po = out + ((size_t)(b * 1024 + l) * 1024 + mbase) * 8 + lane * 16;
            *(float4*)(po)      = o0;
            *(float4*)(po + 4)  = o1;
            *(float4*)(po + 8)  = o2;
            *(float4*)(po + 12) = o3;
        }
    }
}

extern "C" void kernel_launch(void* const* d_in, const int* in_sizes, int n_in,
                              void* d_out, int out_size, void* d_ws, size_t ws_size,
                              hipStream_t stream) {
    (void)in_sizes; (void)n_in; (void)out_size;
    const float* sh = (const float*)d_in[0];
    const float* eh = (const float*)d_in[1];
    const float* v  = (const float*)d_in[2];
    float* out = (float*)d_out;

    const size_t need = 32768 * sizeof(float)
                      + 2 * (size_t)16384 * 512 * sizeof(unsigned short); // 33,685,504 B
    if (ws_size >= need) {
        float* sums = (float*)d_ws;
        unsigned short* Aw = (unsigned short*)((char*)d_ws + 32768 * sizeof(float));
        unsigned short* Bw = Aw + (size_t)16384 * 512;
        prep_k<<<4096, 256, 0, stream>>>(sh, eh, v, sums, Aw, Bw);
        gemm5_k<<<512, 512, 0, stream>>>(Aw, Bw, sums, out);
    } else {
        float* ws = (float*)d_ws;   // 32768 floats = 128 KB
        sums_k<<<4096, 256, 0, stream>>>(sh, eh, v, ws);
        gemm_k<<<256, 512, 0, stream>>>(sh, eh, v, ws, out);
    }
}